// Round 1
// baseline (635.762 us; speedup 1.0000x reference)
//
#include <hip/hip_runtime.h>
#include <math.h>

#define NN 50000
#define NE 640000

// ---------------- CSR build ----------------

__global__ void count_kernel(const int* __restrict__ dst, int* __restrict__ cnt, int E) {
    int e = blockIdx.x * blockDim.x + threadIdx.x;
    if (e < E) atomicAdd(&cnt[dst[e]], 1);
}

// Single-block exclusive scan over N counts -> row_ptr, tmp_ptr; also dinv = rsqrt(cnt+1)
__global__ __launch_bounds__(1024) void scan_kernel(const int* __restrict__ cnt,
                                                    int* __restrict__ row_ptr,
                                                    int* __restrict__ tmp_ptr,
                                                    float* __restrict__ dinv,
                                                    int N, int E) {
    __shared__ int partial[1024];
    int tid = threadIdx.x;
    const int CHUNK = (N + 1023) / 1024;
    int base = tid * CHUNK;
    int s = 0;
    for (int i = 0; i < CHUNK; ++i) {
        int idx = base + i;
        if (idx < N) s += cnt[idx];
    }
    partial[tid] = s;
    __syncthreads();
    // Hillis-Steele inclusive scan
    for (int off = 1; off < 1024; off <<= 1) {
        int v = (tid >= off) ? partial[tid - off] : 0;
        __syncthreads();
        partial[tid] += v;
        __syncthreads();
    }
    int run = (tid > 0) ? partial[tid - 1] : 0;  // exclusive base for this chunk
    for (int i = 0; i < CHUNK; ++i) {
        int idx = base + i;
        if (idx < N) {
            row_ptr[idx] = run;
            tmp_ptr[idx] = run;
            int c = cnt[idx];
            run += c;
            dinv[idx] = rsqrtf((float)c + 1.0f);
        }
    }
    if (tid == 0) row_ptr[N] = E;
}

__global__ void fill_kernel(const int* __restrict__ src, const int* __restrict__ dst,
                            int* __restrict__ tmp_ptr, int* __restrict__ col, int E) {
    int e = blockIdx.x * blockDim.x + threadIdx.x;
    if (e < E) {
        int d = dst[e];
        int pos = atomicAdd(&tmp_ptr[d], 1);
        col[pos] = src[e];
    }
}

// ---------------- GEMM: G[r][c] = dinv[r] * sum_k X[r][k] * W[k][c], K = 128 ----------------
// Block: 256 threads, 64 rows per block, full NOUT columns. W fully in LDS.

template <int NOUT>
__global__ __launch_bounds__(256) void gemm_scale_kernel(const float* __restrict__ X,
                                                         const float* __restrict__ W,
                                                         const float* __restrict__ dinv,
                                                         float* __restrict__ G, int N) {
    constexpr int K = 128;
    constexpr int TN = NOUT / 16;  // 8 (NOUT=128) or 4 (NOUT=64)
    __shared__ float Ws[K * NOUT];
    __shared__ float Xs[64][132];  // +4 pad: 2-way bank alias only (free)

    int tid = threadIdx.x;

    // Load W (K*NOUT floats) with float4, coalesced
    for (int i = tid * 4; i < K * NOUT; i += 256 * 4) {
        *reinterpret_cast<float4*>(&Ws[i]) = *reinterpret_cast<const float4*>(&W[i]);
    }

    // Load X tile: rows row0..row0+63, 128 K each; float4 per thread-iter, coalesced
    int row0 = blockIdx.x * 64;
    for (int idx4 = tid; idx4 < 64 * (K / 4); idx4 += 256) {
        int m = idx4 >> 5;           // idx4 / 32
        int k4 = (idx4 & 31) << 2;   // (idx4 % 32) * 4
        int r = row0 + m;
        float4 v = make_float4(0.f, 0.f, 0.f, 0.f);
        if (r < N) v = *reinterpret_cast<const float4*>(&X[(size_t)r * K + k4]);
        *reinterpret_cast<float4*>(&Xs[m][k4]) = v;
    }
    __syncthreads();

    int tx = tid & 15;   // column group
    int ty = tid >> 4;   // row group
    int c0 = tx * TN;
    int m0 = ty * 4;

    float acc[4][TN];
#pragma unroll
    for (int j = 0; j < 4; ++j)
#pragma unroll
        for (int c = 0; c < TN; ++c) acc[j][c] = 0.f;

#pragma unroll 8
    for (int k = 0; k < K; ++k) {
        float xv[4];
#pragma unroll
        for (int j = 0; j < 4; ++j) xv[j] = Xs[m0 + j][k];
        float wv[TN];
#pragma unroll
        for (int c = 0; c < TN; c += 4)
            *reinterpret_cast<float4*>(&wv[c]) =
                *reinterpret_cast<const float4*>(&Ws[k * NOUT + c0 + c]);
#pragma unroll
        for (int j = 0; j < 4; ++j)
#pragma unroll
            for (int c = 0; c < TN; ++c) acc[j][c] = fmaf(xv[j], wv[c], acc[j][c]);
    }

#pragma unroll
    for (int j = 0; j < 4; ++j) {
        int r = row0 + m0 + j;
        if (r < N) {
            float s = dinv[r];
            float4 o;
#pragma unroll
            for (int c = 0; c < TN; c += 4) {
                o.x = s * acc[j][c + 0];
                o.y = s * acc[j][c + 1];
                o.z = s * acc[j][c + 2];
                o.w = s * acc[j][c + 3];
                *reinterpret_cast<float4*>(&G[(size_t)r * NOUT + c0 + c]) = o;
            }
        }
    }
}

// ---------------- Aggregate: Out[i] = act(dinv[i]*(sum_{j in N(i)} G[j] + G[i]) + b) ----------------
// One wave (64 lanes) per node.

template <int F, bool RELU>
__global__ __launch_bounds__(256) void aggregate_kernel(const float* __restrict__ G,
                                                        const float* __restrict__ dinv,
                                                        const int* __restrict__ row_ptr,
                                                        const int* __restrict__ col,
                                                        const float* __restrict__ bias,
                                                        float* __restrict__ Out, int N) {
    int node = blockIdx.x * (blockDim.x >> 6) + (threadIdx.x >> 6);
    int lane = threadIdx.x & 63;
    if (node >= N) return;
    int beg = row_ptr[node];
    int end = row_ptr[node + 1];

    if (F == 128) {
        const float2* Gp = reinterpret_cast<const float2*>(G);
        float2 acc = Gp[(size_t)node * 64 + lane];  // self contribution g_i
        for (int e = beg; e < end; ++e) {
            int j = col[e];
            float2 v = Gp[(size_t)j * 64 + lane];
            acc.x += v.x;
            acc.y += v.y;
        }
        float s = dinv[node];
        float2 bb = reinterpret_cast<const float2*>(bias)[lane];
        float ox = fmaf(s, acc.x, bb.x);
        float oy = fmaf(s, acc.y, bb.y);
        if (RELU) {
            ox = fmaxf(ox, 0.f);
            oy = fmaxf(oy, 0.f);
        }
        reinterpret_cast<float2*>(Out)[(size_t)node * 64 + lane] = make_float2(ox, oy);
    } else {  // F == 64
        float acc = G[(size_t)node * F + lane];
        for (int e = beg; e < end; ++e) {
            int j = col[e];
            acc += G[(size_t)j * F + lane];
        }
        float o = fmaf(dinv[node], acc, bias[lane]);
        if (RELU) o = fmaxf(o, 0.f);
        Out[(size_t)node * F + lane] = o;
    }
}

// ---------------- launch ----------------

extern "C" void kernel_launch(void* const* d_in, const int* in_sizes, int n_in,
                              void* d_out, int out_size, void* d_ws, size_t ws_size,
                              hipStream_t stream) {
    const float* x  = (const float*)d_in[0];
    const int*  edge = (const int*)d_in[1];   // [2, E] int32 (jax default x64 disabled)
    const float* W1 = (const float*)d_in[2];
    const float* b1 = (const float*)d_in[3];
    const float* W2 = (const float*)d_in[4];
    const float* b2 = (const float*)d_in[5];
    const float* W3 = (const float*)d_in[6];
    const float* b3 = (const float*)d_in[7];
    float* out = (float*)d_out;

    const int N = NN, E = NE;
    const int* src = edge;
    const int* dst = edge + E;

    // ws layout, 256B-aligned slices
    size_t off = 0;
    auto alloc = [&](size_t bytes) {
        void* p = (char*)d_ws + off;
        off = (off + bytes + 255) & ~(size_t)255;
        return p;
    };
    int*   cnt     = (int*)alloc((size_t)N * 4);
    int*   row_ptr = (int*)alloc((size_t)(N + 1) * 4);
    int*   tmp_ptr = (int*)alloc((size_t)N * 4);
    int*   colv    = (int*)alloc((size_t)E * 4);
    float* dinv    = (float*)alloc((size_t)N * 4);
    float* g       = (float*)alloc((size_t)N * 128 * 4);
    float* h       = (float*)alloc((size_t)N * 128 * 4);
    (void)ws_size; (void)in_sizes; (void)n_in; (void)out_size;

    // CSR build (per call: ws is re-poisoned)
    hipMemsetAsync(cnt, 0, (size_t)N * 4, stream);
    count_kernel<<<(E + 255) / 256, 256, 0, stream>>>(dst, cnt, E);
    scan_kernel<<<1, 1024, 0, stream>>>(cnt, row_ptr, tmp_ptr, dinv, N, E);
    fill_kernel<<<(E + 255) / 256, 256, 0, stream>>>(src, dst, tmp_ptr, colv, E);

    dim3 gemm_grid((N + 63) / 64);
    dim3 agg_grid((N + 3) / 4);

    // Layer 1: g = dinv * (x @ W1); h = relu(dinv*(agg g) + b1)
    gemm_scale_kernel<128><<<gemm_grid, 256, 0, stream>>>(x, W1, dinv, g, N);
    aggregate_kernel<128, true><<<agg_grid, 256, 0, stream>>>(g, dinv, row_ptr, colv, b1, h, N);

    // Layer 2
    gemm_scale_kernel<128><<<gemm_grid, 256, 0, stream>>>(h, W2, dinv, g, N);
    aggregate_kernel<128, true><<<agg_grid, 256, 0, stream>>>(g, dinv, row_ptr, colv, b2, h, N);

    // Layer 3 (no relu) -> out
    gemm_scale_kernel<64><<<gemm_grid, 256, 0, stream>>>(h, W3, dinv, g, N);
    aggregate_kernel<64, false><<<agg_grid, 256, 0, stream>>>(g, dinv, row_ptr, colv, b3, out, N);
}

// Round 3
// 493.539 us; speedup vs baseline: 1.2882x; 1.2882x over previous
//
#include <hip/hip_runtime.h>
#include <math.h>

#define NN 50000
#define NE 640000

// ---------------- CSR build ----------------

__global__ void count_kernel(const int* __restrict__ dst, int* __restrict__ cnt, int E) {
    int e = blockIdx.x * blockDim.x + threadIdx.x;
    if (e < E) atomicAdd(&cnt[dst[e]], 1);
}

// ---- decoupled 3-kernel scan over cnt[N] -> row_ptr/tmp_ptr (+dinv) ----
// Stage 1: each block reduces 1024 counts -> blk_sums[blockIdx]
__global__ __launch_bounds__(256) void block_reduce_kernel(const int* __restrict__ cnt,
                                                           int* __restrict__ blk_sums, int N) {
    __shared__ int red[256];
    int tid = threadIdx.x;
    int base = blockIdx.x * 1024 + tid * 4;
    int s = 0;
    if (base + 3 < N) {
        int4 v = *reinterpret_cast<const int4*>(&cnt[base]);
        s = v.x + v.y + v.z + v.w;
    } else {
        for (int i = 0; i < 4; ++i)
            if (base + i < N) s += cnt[base + i];
    }
    red[tid] = s;
    __syncthreads();
    for (int off = 128; off > 0; off >>= 1) {
        if (tid < off) red[tid] += red[tid + off];
        __syncthreads();
    }
    if (tid == 0) blk_sums[blockIdx.x] = red[0];
}

// Stage 2: single wave exclusive-scans blk_sums (nblk <= 64)
__global__ __launch_bounds__(64) void scan_sums_kernel(int* __restrict__ blk_sums, int nblk) {
    int lane = threadIdx.x;
    int v = (lane < nblk) ? blk_sums[lane] : 0;
    for (int off = 1; off < 64; off <<= 1) {
        int u = __shfl_up(v, off);
        if (lane >= off) v += u;
    }
    int ex = __shfl_up(v, 1);
    if (lane == 0) ex = 0;
    if (lane < nblk) blk_sums[lane] = ex;
}

// Stage 3: per-block scan (4 elems/thread, wave shfl scan + warp-sum combine + block offset)
__global__ __launch_bounds__(256) void block_scan_kernel(const int* __restrict__ cnt,
                                                         const int* __restrict__ blk_offs,
                                                         int* __restrict__ row_ptr,
                                                         int* __restrict__ tmp_ptr,
                                                         float* __restrict__ dinv,
                                                         int N, int E) {
    __shared__ int warp_sums[4];
    int tid = threadIdx.x;
    int base = blockIdx.x * 1024 + tid * 4;
    int c[4];
    int s = 0;
#pragma unroll
    for (int i = 0; i < 4; ++i) {
        int idx = base + i;
        c[i] = (idx < N) ? cnt[idx] : 0;
        s += c[i];
    }
    int lane = tid & 63;
    int wv = tid >> 6;
    int v = s;
    for (int off = 1; off < 64; off <<= 1) {
        int u = __shfl_up(v, off);
        if (lane >= off) v += u;
    }
    if (lane == 63) warp_sums[wv] = v;
    __syncthreads();
    int woff = 0;
    for (int w = 0; w < wv; ++w) woff += warp_sums[w];
    int run = blk_offs[blockIdx.x] + woff + (v - s);  // exclusive prefix for this thread
#pragma unroll
    for (int i = 0; i < 4; ++i) {
        int idx = base + i;
        if (idx < N) {
            row_ptr[idx] = run;
            tmp_ptr[idx] = run;
            run += c[i];
            dinv[idx] = rsqrtf((float)c[i] + 1.0f);
        }
    }
    if (blockIdx.x == 0 && tid == 0) row_ptr[N] = E;
}

__global__ void fill_kernel(const int* __restrict__ src, const int* __restrict__ dst,
                            int* __restrict__ tmp_ptr, int* __restrict__ col, int E) {
    int e = blockIdx.x * blockDim.x + threadIdx.x;
    if (e < E) {
        int d = dst[e];
        int pos = atomicAdd(&tmp_ptr[d], 1);
        col[pos] = src[e];
    }
}

// ---------------- GEMM: G[r][c] = dinv[r] * sum_k X[r][k] * W[k][c], K = 128 ----------------

template <int NOUT>
__global__ __launch_bounds__(256) void gemm_scale_kernel(const float* __restrict__ X,
                                                         const float* __restrict__ W,
                                                         const float* __restrict__ dinv,
                                                         float* __restrict__ G, int N) {
    constexpr int K = 128;
    constexpr int TN = NOUT / 16;  // 8 (NOUT=128) or 4 (NOUT=64)
    __shared__ float Ws[K * NOUT];
    __shared__ float Xs[64][132];

    int tid = threadIdx.x;

    for (int i = tid * 4; i < K * NOUT; i += 256 * 4) {
        *reinterpret_cast<float4*>(&Ws[i]) = *reinterpret_cast<const float4*>(&W[i]);
    }

    int row0 = blockIdx.x * 64;
    for (int idx4 = tid; idx4 < 64 * (K / 4); idx4 += 256) {
        int m = idx4 >> 5;
        int k4 = (idx4 & 31) << 2;
        int r = row0 + m;
        float4 v = make_float4(0.f, 0.f, 0.f, 0.f);
        if (r < N) v = *reinterpret_cast<const float4*>(&X[(size_t)r * K + k4]);
        *reinterpret_cast<float4*>(&Xs[m][k4]) = v;
    }
    __syncthreads();

    int tx = tid & 15;
    int ty = tid >> 4;
    int c0 = tx * TN;
    int m0 = ty * 4;

    float acc[4][TN];
#pragma unroll
    for (int j = 0; j < 4; ++j)
#pragma unroll
        for (int c = 0; c < TN; ++c) acc[j][c] = 0.f;

#pragma unroll 8
    for (int k = 0; k < K; ++k) {
        float xv[4];
#pragma unroll
        for (int j = 0; j < 4; ++j) xv[j] = Xs[m0 + j][k];
        float wv[TN];
#pragma unroll
        for (int c = 0; c < TN; c += 4)
            *reinterpret_cast<float4*>(&wv[c]) =
                *reinterpret_cast<const float4*>(&Ws[k * NOUT + c0 + c]);
#pragma unroll
        for (int j = 0; j < 4; ++j)
#pragma unroll
            for (int c = 0; c < TN; ++c) acc[j][c] = fmaf(xv[j], wv[c], acc[j][c]);
    }

#pragma unroll
    for (int j = 0; j < 4; ++j) {
        int r = row0 + m0 + j;
        if (r < N) {
            float s = dinv[r];
            float4 o;
#pragma unroll
            for (int c = 0; c < TN; c += 4) {
                o.x = s * acc[j][c + 0];
                o.y = s * acc[j][c + 1];
                o.z = s * acc[j][c + 2];
                o.w = s * acc[j][c + 3];
                *reinterpret_cast<float4*>(&G[(size_t)r * NOUT + c0 + c]) = o;
            }
        }
    }
}

// ---------------- Aggregate: Out[i] = act(dinv[i]*(sum_{j in N(i)} G[j] + G[i]) + b) ----------------

template <int F, bool RELU>
__global__ __launch_bounds__(256) void aggregate_kernel(const float* __restrict__ G,
                                                        const float* __restrict__ dinv,
                                                        const int* __restrict__ row_ptr,
                                                        const int* __restrict__ col,
                                                        const float* __restrict__ bias,
                                                        float* __restrict__ Out, int N) {
    int node = blockIdx.x * (blockDim.x >> 6) + (threadIdx.x >> 6);
    int lane = threadIdx.x & 63;
    if (node >= N) return;
    int beg = row_ptr[node];
    int end = row_ptr[node + 1];

    if (F == 128) {
        const float2* Gp = reinterpret_cast<const float2*>(G);
        float2 acc = Gp[(size_t)node * 64 + lane];
        for (int e = beg; e < end; ++e) {
            int j = col[e];
            float2 v = Gp[(size_t)j * 64 + lane];
            acc.x += v.x;
            acc.y += v.y;
        }
        float s = dinv[node];
        float2 bb = reinterpret_cast<const float2*>(bias)[lane];
        float ox = fmaf(s, acc.x, bb.x);
        float oy = fmaf(s, acc.y, bb.y);
        if (RELU) {
            ox = fmaxf(ox, 0.f);
            oy = fmaxf(oy, 0.f);
        }
        reinterpret_cast<float2*>(Out)[(size_t)node * 64 + lane] = make_float2(ox, oy);
    } else {  // F == 64
        float acc = G[(size_t)node * F + lane];
        for (int e = beg; e < end; ++e) {
            int j = col[e];
            acc += G[(size_t)j * F + lane];
        }
        float o = fmaf(dinv[node], acc, bias[lane]);
        if (RELU) o = fmaxf(o, 0.f);
        Out[(size_t)node * F + lane] = o;
    }
}

// ---------------- launch ----------------

extern "C" void kernel_launch(void* const* d_in, const int* in_sizes, int n_in,
                              void* d_out, int out_size, void* d_ws, size_t ws_size,
                              hipStream_t stream) {
    const float* x  = (const float*)d_in[0];
    const int*  edge = (const int*)d_in[1];
    const float* W1 = (const float*)d_in[2];
    const float* b1 = (const float*)d_in[3];
    const float* W2 = (const float*)d_in[4];
    const float* b2 = (const float*)d_in[5];
    const float* W3 = (const float*)d_in[6];
    const float* b3 = (const float*)d_in[7];
    float* out = (float*)d_out;

    const int N = NN, E = NE;
    const int* src = edge;
    const int* dst = edge + E;
    const int NBLK = (N + 1023) / 1024;  // 49

    size_t off = 0;
    auto alloc = [&](size_t bytes) {
        void* p = (char*)d_ws + off;
        off = (off + bytes + 255) & ~(size_t)255;
        return p;
    };
    int*   cnt      = (int*)alloc((size_t)N * 4);
    int*   row_ptr  = (int*)alloc((size_t)(N + 1) * 4);
    int*   tmp_ptr  = (int*)alloc((size_t)N * 4);
    int*   colv     = (int*)alloc((size_t)E * 4);
    float* dinv     = (float*)alloc((size_t)N * 4);
    int*   blk_sums = (int*)alloc((size_t)NBLK * 4);
    float* g        = (float*)alloc((size_t)N * 128 * 4);
    float* h        = (float*)alloc((size_t)N * 128 * 4);
    (void)ws_size; (void)in_sizes; (void)n_in; (void)out_size;

    hipMemsetAsync(cnt, 0, (size_t)N * 4, stream);
    count_kernel<<<(E + 255) / 256, 256, 0, stream>>>(dst, cnt, E);
    block_reduce_kernel<<<NBLK, 256, 0, stream>>>(cnt, blk_sums, N);
    scan_sums_kernel<<<1, 64, 0, stream>>>(blk_sums, NBLK);
    block_scan_kernel<<<NBLK, 256, 0, stream>>>(cnt, blk_sums, row_ptr, tmp_ptr, dinv, N, E);
    fill_kernel<<<(E + 255) / 256, 256, 0, stream>>>(src, dst, tmp_ptr, colv, E);

    dim3 gemm_grid((N + 63) / 64);
    dim3 agg_grid((N + 3) / 4);

    gemm_scale_kernel<128><<<gemm_grid, 256, 0, stream>>>(x, W1, dinv, g, N);
    aggregate_kernel<128, true><<<agg_grid, 256, 0, stream>>>(g, dinv, row_ptr, colv, b1, h, N);

    gemm_scale_kernel<128><<<gemm_grid, 256, 0, stream>>>(h, W2, dinv, g, N);
    aggregate_kernel<128, true><<<agg_grid, 256, 0, stream>>>(g, dinv, row_ptr, colv, b2, h, N);

    gemm_scale_kernel<64><<<gemm_grid, 256, 0, stream>>>(h, W3, dinv, g, N);
    aggregate_kernel<64, false><<<agg_grid, 256, 0, stream>>>(g, dinv, row_ptr, colv, b3, out, N);
}

// Round 4
// 423.954 us; speedup vs baseline: 1.4996x; 1.1641x over previous
//
#include <hip/hip_runtime.h>
#include <math.h>

#define NN 50000
#define NE 640000

// ---------------- CSR build ----------------

__global__ void count_kernel(const int* __restrict__ dst, int* __restrict__ cnt, int E) {
    int e = blockIdx.x * blockDim.x + threadIdx.x;
    if (e < E) atomicAdd(&cnt[dst[e]], 1);
}

// ---- decoupled 3-kernel scan over cnt[N] -> row_ptr/tmp_ptr (+dinv) ----
__global__ __launch_bounds__(256) void block_reduce_kernel(const int* __restrict__ cnt,
                                                           int* __restrict__ blk_sums, int N) {
    __shared__ int red[256];
    int tid = threadIdx.x;
    int base = blockIdx.x * 1024 + tid * 4;
    int s = 0;
    if (base + 3 < N) {
        int4 v = *reinterpret_cast<const int4*>(&cnt[base]);
        s = v.x + v.y + v.z + v.w;
    } else {
        for (int i = 0; i < 4; ++i)
            if (base + i < N) s += cnt[base + i];
    }
    red[tid] = s;
    __syncthreads();
    for (int off = 128; off > 0; off >>= 1) {
        if (tid < off) red[tid] += red[tid + off];
        __syncthreads();
    }
    if (tid == 0) blk_sums[blockIdx.x] = red[0];
}

__global__ __launch_bounds__(64) void scan_sums_kernel(int* __restrict__ blk_sums, int nblk) {
    int lane = threadIdx.x;
    int v = (lane < nblk) ? blk_sums[lane] : 0;
    for (int off = 1; off < 64; off <<= 1) {
        int u = __shfl_up(v, off);
        if (lane >= off) v += u;
    }
    int ex = __shfl_up(v, 1);
    if (lane == 0) ex = 0;
    if (lane < nblk) blk_sums[lane] = ex;
}

__global__ __launch_bounds__(256) void block_scan_kernel(const int* __restrict__ cnt,
                                                         const int* __restrict__ blk_offs,
                                                         int* __restrict__ row_ptr,
                                                         int* __restrict__ tmp_ptr,
                                                         float* __restrict__ dinv,
                                                         int N, int E) {
    __shared__ int warp_sums[4];
    int tid = threadIdx.x;
    int base = blockIdx.x * 1024 + tid * 4;
    int c[4];
    int s = 0;
#pragma unroll
    for (int i = 0; i < 4; ++i) {
        int idx = base + i;
        c[i] = (idx < N) ? cnt[idx] : 0;
        s += c[i];
    }
    int lane = tid & 63;
    int wv = tid >> 6;
    int v = s;
    for (int off = 1; off < 64; off <<= 1) {
        int u = __shfl_up(v, off);
        if (lane >= off) v += u;
    }
    if (lane == 63) warp_sums[wv] = v;
    __syncthreads();
    int woff = 0;
    for (int w = 0; w < wv; ++w) woff += warp_sums[w];
    int run = blk_offs[blockIdx.x] + woff + (v - s);
#pragma unroll
    for (int i = 0; i < 4; ++i) {
        int idx = base + i;
        if (idx < N) {
            row_ptr[idx] = run;
            tmp_ptr[idx] = run;
            run += c[i];
            dinv[idx] = rsqrtf((float)c[i] + 1.0f);
        }
    }
    if (blockIdx.x == 0 && tid == 0) row_ptr[N] = E;
}

__global__ void fill_kernel(const int* __restrict__ src, const int* __restrict__ dst,
                            int* __restrict__ tmp_ptr, int* __restrict__ col, int E) {
    int e = blockIdx.x * blockDim.x + threadIdx.x;
    if (e < E) {
        int d = dst[e];
        int pos = atomicAdd(&tmp_ptr[d], 1);
        col[pos] = src[e];
    }
}

// ---------------- GEMM: G[r][c] = dinv[r] * sum_k X[r][k] * W[k][c], K = 128 ----------------
// 256 threads, 64 rows/block. Column split into two half-blocks (tx*4, 64+tx*4):
// Ws b128 reads land 2-way bank-aliased (free) instead of 4-way. k-unrolled x4.

template <int NOUT>
__global__ __launch_bounds__(256) void gemm_scale_kernel(const float* __restrict__ X,
                                                         const float* __restrict__ W,
                                                         const float* __restrict__ dinv,
                                                         float* __restrict__ G, int N) {
    constexpr int K = 128;
    __shared__ float Ws[K * NOUT];
    __shared__ float Xs[64][132];  // 132*4=528B row stride: 16B-aligned, 2-way bank alias

    int tid = threadIdx.x;

    for (int i = tid * 4; i < K * NOUT; i += 256 * 4) {
        *reinterpret_cast<float4*>(&Ws[i]) = *reinterpret_cast<const float4*>(&W[i]);
    }

    int row0 = blockIdx.x * 64;
    for (int idx4 = tid; idx4 < 64 * (K / 4); idx4 += 256) {
        int m = idx4 >> 5;
        int k4 = (idx4 & 31) << 2;
        int r = row0 + m;
        float4 v = make_float4(0.f, 0.f, 0.f, 0.f);
        if (r < N) v = *reinterpret_cast<const float4*>(&X[(size_t)r * K + k4]);
        *reinterpret_cast<float4*>(&Xs[m][k4]) = v;
    }
    __syncthreads();

    int tx = tid & 15;
    int ty = tid >> 4;
    int m0 = ty * 4;

    if (NOUT == 128) {
        float acc[4][8];
#pragma unroll
        for (int j = 0; j < 4; ++j)
#pragma unroll
            for (int c = 0; c < 8; ++c) acc[j][c] = 0.f;

        for (int k = 0; k < K; k += 4) {
            float4 xv[4];
#pragma unroll
            for (int j = 0; j < 4; ++j)
                xv[j] = *reinterpret_cast<const float4*>(&Xs[m0 + j][k]);
#pragma unroll
            for (int kk = 0; kk < 4; ++kk) {
                float4 wa = *reinterpret_cast<const float4*>(&Ws[(k + kk) * 128 + tx * 4]);
                float4 wb = *reinterpret_cast<const float4*>(&Ws[(k + kk) * 128 + 64 + tx * 4]);
#pragma unroll
                for (int j = 0; j < 4; ++j) {
                    float xs = reinterpret_cast<const float*>(&xv[j])[kk];
                    acc[j][0] = fmaf(xs, wa.x, acc[j][0]);
                    acc[j][1] = fmaf(xs, wa.y, acc[j][1]);
                    acc[j][2] = fmaf(xs, wa.z, acc[j][2]);
                    acc[j][3] = fmaf(xs, wa.w, acc[j][3]);
                    acc[j][4] = fmaf(xs, wb.x, acc[j][4]);
                    acc[j][5] = fmaf(xs, wb.y, acc[j][5]);
                    acc[j][6] = fmaf(xs, wb.z, acc[j][6]);
                    acc[j][7] = fmaf(xs, wb.w, acc[j][7]);
                }
            }
        }

#pragma unroll
        for (int j = 0; j < 4; ++j) {
            int r = row0 + m0 + j;
            if (r < N) {
                float s = dinv[r];
                float4 oa, ob;
                oa.x = s * acc[j][0]; oa.y = s * acc[j][1];
                oa.z = s * acc[j][2]; oa.w = s * acc[j][3];
                ob.x = s * acc[j][4]; ob.y = s * acc[j][5];
                ob.z = s * acc[j][6]; ob.w = s * acc[j][7];
                *reinterpret_cast<float4*>(&G[(size_t)r * 128 + tx * 4]) = oa;
                *reinterpret_cast<float4*>(&G[(size_t)r * 128 + 64 + tx * 4]) = ob;
            }
        }
    } else {  // NOUT == 64
        float acc[4][4];
#pragma unroll
        for (int j = 0; j < 4; ++j)
#pragma unroll
            for (int c = 0; c < 4; ++c) acc[j][c] = 0.f;

        for (int k = 0; k < K; k += 4) {
            float4 xv[4];
#pragma unroll
            for (int j = 0; j < 4; ++j)
                xv[j] = *reinterpret_cast<const float4*>(&Xs[m0 + j][k]);
#pragma unroll
            for (int kk = 0; kk < 4; ++kk) {
                float4 wa = *reinterpret_cast<const float4*>(&Ws[(k + kk) * 64 + tx * 4]);
#pragma unroll
                for (int j = 0; j < 4; ++j) {
                    float xs = reinterpret_cast<const float*>(&xv[j])[kk];
                    acc[j][0] = fmaf(xs, wa.x, acc[j][0]);
                    acc[j][1] = fmaf(xs, wa.y, acc[j][1]);
                    acc[j][2] = fmaf(xs, wa.z, acc[j][2]);
                    acc[j][3] = fmaf(xs, wa.w, acc[j][3]);
                }
            }
        }

#pragma unroll
        for (int j = 0; j < 4; ++j) {
            int r = row0 + m0 + j;
            if (r < N) {
                float s = dinv[r];
                float4 oa;
                oa.x = s * acc[j][0]; oa.y = s * acc[j][1];
                oa.z = s * acc[j][2]; oa.w = s * acc[j][3];
                *reinterpret_cast<float4*>(&G[(size_t)r * 64 + tx * 4]) = oa;
            }
        }
    }
}

// ---------------- Aggregate: Out[i] = act(dinv[i]*(sum_{j in N(i)} G[j] + G[i]) + b) ----------------
// One wave per node; 4 gathers in flight (4 independent accumulators).

template <int F, bool RELU>
__global__ __launch_bounds__(256) void aggregate_kernel(const float* __restrict__ G,
                                                        const float* __restrict__ dinv,
                                                        const int* __restrict__ row_ptr,
                                                        const int* __restrict__ col,
                                                        const float* __restrict__ bias,
                                                        float* __restrict__ Out, int N) {
    int node = blockIdx.x * 4 + (threadIdx.x >> 6);
    int lane = threadIdx.x & 63;
    if (node >= N) return;
    int beg = row_ptr[node];
    int end = row_ptr[node + 1];

    if (F == 128) {
        const float2* Gp = reinterpret_cast<const float2*>(G);
        float2 a0 = Gp[(size_t)node * 64 + lane];  // self contribution
        float2 a1 = make_float2(0.f, 0.f);
        float2 a2 = make_float2(0.f, 0.f);
        float2 a3 = make_float2(0.f, 0.f);
        for (int e = beg; e < end; e += 4) {
            int last = end - 1;
            int j0 = col[e];
            int j1 = col[min(e + 1, last)];
            int j2 = col[min(e + 2, last)];
            int j3 = col[min(e + 3, last)];
            float2 v0 = Gp[(size_t)j0 * 64 + lane];
            float2 v1 = Gp[(size_t)j1 * 64 + lane];
            float2 v2 = Gp[(size_t)j2 * 64 + lane];
            float2 v3 = Gp[(size_t)j3 * 64 + lane];
            a0.x += v0.x; a0.y += v0.y;
            if (e + 1 < end) { a1.x += v1.x; a1.y += v1.y; }
            if (e + 2 < end) { a2.x += v2.x; a2.y += v2.y; }
            if (e + 3 < end) { a3.x += v3.x; a3.y += v3.y; }
        }
        a0.x += a1.x + a2.x + a3.x;
        a0.y += a1.y + a2.y + a3.y;
        float s = dinv[node];
        float2 bb = reinterpret_cast<const float2*>(bias)[lane];
        float ox = fmaf(s, a0.x, bb.x);
        float oy = fmaf(s, a0.y, bb.y);
        if (RELU) {
            ox = fmaxf(ox, 0.f);
            oy = fmaxf(oy, 0.f);
        }
        reinterpret_cast<float2*>(Out)[(size_t)node * 64 + lane] = make_float2(ox, oy);
    } else {  // F == 64
        float a0 = G[(size_t)node * F + lane];
        float a1 = 0.f, a2 = 0.f, a3 = 0.f;
        for (int e = beg; e < end; e += 4) {
            int last = end - 1;
            int j0 = col[e];
            int j1 = col[min(e + 1, last)];
            int j2 = col[min(e + 2, last)];
            int j3 = col[min(e + 3, last)];
            float v0 = G[(size_t)j0 * F + lane];
            float v1 = G[(size_t)j1 * F + lane];
            float v2 = G[(size_t)j2 * F + lane];
            float v3 = G[(size_t)j3 * F + lane];
            a0 += v0;
            if (e + 1 < end) a1 += v1;
            if (e + 2 < end) a2 += v2;
            if (e + 3 < end) a3 += v3;
        }
        a0 += a1 + a2 + a3;
        float o = fmaf(dinv[node], a0, bias[lane]);
        if (RELU) o = fmaxf(o, 0.f);
        Out[(size_t)node * F + lane] = o;
    }
}

// ---------------- launch ----------------

extern "C" void kernel_launch(void* const* d_in, const int* in_sizes, int n_in,
                              void* d_out, int out_size, void* d_ws, size_t ws_size,
                              hipStream_t stream) {
    const float* x  = (const float*)d_in[0];
    const int*  edge = (const int*)d_in[1];
    const float* W1 = (const float*)d_in[2];
    const float* b1 = (const float*)d_in[3];
    const float* W2 = (const float*)d_in[4];
    const float* b2 = (const float*)d_in[5];
    const float* W3 = (const float*)d_in[6];
    const float* b3 = (const float*)d_in[7];
    float* out = (float*)d_out;

    const int N = NN, E = NE;
    const int* src = edge;
    const int* dst = edge + E;
    const int NBLK = (N + 1023) / 1024;  // 49

    size_t off = 0;
    auto alloc = [&](size_t bytes) {
        void* p = (char*)d_ws + off;
        off = (off + bytes + 255) & ~(size_t)255;
        return p;
    };
    int*   cnt      = (int*)alloc((size_t)N * 4);
    int*   row_ptr  = (int*)alloc((size_t)(N + 1) * 4);
    int*   tmp_ptr  = (int*)alloc((size_t)N * 4);
    int*   colv     = (int*)alloc((size_t)E * 4);
    float* dinv     = (float*)alloc((size_t)N * 4);
    int*   blk_sums = (int*)alloc((size_t)NBLK * 4);
    float* g        = (float*)alloc((size_t)N * 128 * 4);
    float* h        = (float*)alloc((size_t)N * 128 * 4);
    (void)ws_size; (void)in_sizes; (void)n_in; (void)out_size;

    hipMemsetAsync(cnt, 0, (size_t)N * 4, stream);
    count_kernel<<<(E + 255) / 256, 256, 0, stream>>>(dst, cnt, E);
    block_reduce_kernel<<<NBLK, 256, 0, stream>>>(cnt, blk_sums, N);
    scan_sums_kernel<<<1, 64, 0, stream>>>(blk_sums, NBLK);
    block_scan_kernel<<<NBLK, 256, 0, stream>>>(cnt, blk_sums, row_ptr, tmp_ptr, dinv, N, E);
    fill_kernel<<<(E + 255) / 256, 256, 0, stream>>>(src, dst, tmp_ptr, colv, E);

    dim3 gemm_grid((N + 63) / 64);
    dim3 agg_grid((N + 3) / 4);

    gemm_scale_kernel<128><<<gemm_grid, 256, 0, stream>>>(x, W1, dinv, g, N);
    aggregate_kernel<128, true><<<agg_grid, 256, 0, stream>>>(g, dinv, row_ptr, colv, b1, h, N);

    gemm_scale_kernel<128><<<gemm_grid, 256, 0, stream>>>(h, W2, dinv, g, N);
    aggregate_kernel<128, true><<<agg_grid, 256, 0, stream>>>(g, dinv, row_ptr, colv, b2, h, N);

    gemm_scale_kernel<64><<<gemm_grid, 256, 0, stream>>>(h, W3, dinv, g, N);
    aggregate_kernel<64, false><<<agg_grid, 256, 0, stream>>>(g, dinv, row_ptr, colv, b3, out, N);
}